// Round 13
// baseline (2659.990 us; speedup 1.0000x reference)
//
#include <hip/hip_runtime.h>
#include <math.h>

// FWI forward: 10 shots, 1000 steps, padded grid 130x160 (NBC=30).
// R13 = R12 structure + packed-FP32 arithmetic core via inline asm.
// R12 counters showed ~17 VALU instr/cell: hipcc did NOT form v_pk_*_f32
// from f2 ext-vectors. Here the 11-op cellq core is explicit
// v_pk_add/mul/fma_f32 on even-aligned f2 pairs (CDNA2+ full-rate packed
// fp32). T2 stream stored NEGATED (kdt-1) so update = pk_fma(t2n, p0,
// pk_mul(t1,c)) — fp-identical to t1*c - t2*p0. Everything else byte-
// identical to R12 (p0 rows 0..1 in P0g grid LDS, rows 2..10 in regs,
// q-lag in-place pA, receivers from regs, zlim=min(130-z0,RH)).

#define SROW 168                 // Ps row stride; col = x + 4
#define PSZ (136 * SROW)         // stored rows -2..133
#define P0G (24 * SROW)          // p0 rows 0,1 of each of 12 groups
#define RH 11                    // rows per thread
#define DTf 0.0008f
#define C2f 1.3333333333333333f  // 4/3
#define C3f (-0.08333333333333333f) // -1/12

typedef __attribute__((ext_vector_type(2))) float f2;

#define LD4(arr, i) (*reinterpret_cast<const float4*>(&(arr)[i]))
#define LDF2(arr, i) (*reinterpret_cast<const f2*>(&(arr)[i]))
#define ST4(arr, i, v) (*reinterpret_cast<float4*>(&(arr)[i]) = (v))

// ---------- setup 1: velmin reduction, Ricker wavelet, source amplitudes ----------
__global__ __launch_bounds__(1024) void fwi_setup1(const float* __restrict__ v,
                                                   float* __restrict__ ws) {
    int tid = threadIdx.x;
    float m = 3.402823466e38f;
    for (int i = tid; i < 7000; i += 1024) m = fminf(m, v[i]);
    #pragma unroll
    for (int off = 32; off > 0; off >>= 1) m = fminf(m, __shfl_down(m, off, 64));
    __shared__ float red[16];
    if ((tid & 63) == 0) red[tid >> 6] = m;
    __syncthreads();
    if (tid == 0) {
        float mm = red[0];
        for (int i = 1; i < 16; ++i) mm = fminf(mm, red[i]);
        ws[1010] = mm * 1000.0f + 3000.0f;   // denormalized velmin
    }
    // Ricker wavelet: nw=111, nc=55, f*dt*pi = 0.06283185307179587
    if (tid < 1000) {
        float w = 0.0f;
        if (tid < 111) {
            float a = (float)(55 - tid) * 0.06283185307179587f;
            float b = a * a;
            w = (1.0f - 2.0f * b) * expf(-b);
        }
        ws[tid] = w;
    }
    // src_amp[l] = ((v[1][11l]*1000+3000)*DT)^2
    if (tid >= 1000 && tid < 1010) {
        int l = tid - 1000;
        float vd = v[100 + 11 * l] * 1000.0f + 3000.0f;
        float bdt = vd * DTf;
        ws[tid] = bdt * bdt;
    }
}

// ---------- setup 2: per-cell constants AL, T1, T2n(= kdt-1); 132-row padded ----------
__global__ __launch_bounds__(256) void fwi_setup2(const float* __restrict__ v,
                                                  const float* __restrict__ ws,
                                                  float* __restrict__ AL,
                                                  float* __restrict__ T1,
                                                  float* __restrict__ T2) {
    int c = blockIdx.x * 256 + threadIdx.x;
    if (c >= 132 * 160) return;
    if (c >= 130 * 160) { AL[c] = 0.0f; T1[c] = 0.0f; T2[c] = 0.0f; return; }
    float velmin = ws[1010];
    int z = c / 160;
    int x = c - z * 160;
    int iz = min(max(z - 30, 0), 69);
    int ix = min(max(x - 30, 0), 99);
    float vd = v[iz * 100 + ix] * 1000.0f + 3000.0f;
    float tt = vd * DTf / 10.0f;       // v*DT/DX
    float al = tt * tt;                // alpha
    int qx = max(29 - x, x - 130);
    int qz = max(29 - z, z - 100);
    int q = (qx >= 0) ? qx : qz;
    float kdt = 0.0f;
    if (q >= 0) {
        float kap3 = 3.0f * velmin * 16.118095650958319f / 580.0f; // 3*velmin*ln(1e7)/(2*290)
        float r = (float)q * (10.0f / 290.0f);
        kdt = kap3 * (r * r) * DTf;
    }
    AL[c] = al;
    T1[c] = 2.0f - 5.0f * al - kdt;    // temp1
    T2[c] = kdt - 1.0f;                // NEGATED temp2: t1*c + t2n*p0 == t1*c - t2*p0
}

// ---- packed fp32 primitives (CDNA2+: full-rate v_pk_*_f32) ----
static __device__ __forceinline__ f2 pk_add(f2 a, f2 b) {
    f2 d; asm("v_pk_add_f32 %0, %1, %2" : "=v"(d) : "v"(a), "v"(b)); return d;
}
static __device__ __forceinline__ f2 pk_mul(f2 a, f2 b) {
    f2 d; asm("v_pk_mul_f32 %0, %1, %2" : "=v"(d) : "v"(a), "v"(b)); return d;
}
static __device__ __forceinline__ f2 pk_fma(f2 a, f2 b, f2 c) {
    f2 d; asm("v_pk_fma_f32 %0, %1, %2, %3" : "=v"(d) : "v"(a), "v"(b), "v"(c)); return d;
}
static __device__ __forceinline__ f2 lo4(float4 v) { f2 r; r.x = v.x; r.y = v.y; return r; }
static __device__ __forceinline__ f2 hi4(float4 v) { f2 r; r.x = v.z; r.y = v.w; return r; }

// one pk pair: lap = C2*((l1+r1)+(u1+d1)) + C3*((l2+r2)+(u2+d2));
// q = t1*c + t2n*p0 + al*lap   (t2n = -(temp2))
static __device__ __forceinline__ f2 cellq_pk(f2 l2, f2 l1, f2 cc, f2 r1, f2 r2,
                                              f2 u1, f2 u2, f2 d1, f2 d2,
                                              f2 al, f2 t1, f2 t2n, f2 p0,
                                              f2 c2v, f2 c3v) {
    f2 A   = pk_add(pk_add(l1, r1), pk_add(u1, d1));
    f2 B   = pk_add(pk_add(l2, r2), pk_add(u2, d2));
    f2 lap = pk_fma(c3v, B, pk_mul(c2v, A));
    f2 ab  = pk_fma(t2n, p0, pk_mul(t1, cc));
    return pk_fma(al, lap, ab);
}

// ---------- main: one block per shot, 1000 steps ----------
__global__ __launch_bounds__(512) void fwi_main(const float4* __restrict__ AL4,
                                                const float4* __restrict__ T14,
                                                const float4* __restrict__ T24,
                                                const float* __restrict__ ws,
                                                float* __restrict__ out) {
    __shared__ float Ps[PSZ];      // p1 mirror, haloed (91,392 B)
    __shared__ float P0g[P0G];     // p0 rows 0,1 per group, grid layout (16,128 B)
    __shared__ float Wv[128];      // Ricker wavelet (nonzero only t < 111)
    const int tid = threadIdx.x;
    const int shot = blockIdx.x;

    for (int i = tid; i < PSZ; i += 512) Ps[i] = 0.0f;
    for (int i = tid; i < P0G; i += 512) P0g[i] = 0.0f;
    if (tid < 128) Wv[tid] = (tid < 111) ? ws[tid] : 0.0f;

    const int g  = tid / 40;            // z-group 0..11 active, >=12 idle
    const int qx = tid - g * 40;        // x-quad 0..39, cells x0 = 4*qx
    const int z0 = g * RH;
    const bool act = (g < 12);
    const float amp = ws[1000 + shot];
    const int xs = 30 + 11 * shot;      // source x (z=31 -> g=2, r=9)
    const bool isrc = act && (g == 2) && (qx == (xs >> 2));
    const int ls = xs & 3;
    const int pc0 = (z0 + 2) * SROW + 4 * qx + 4;  // Ps index of row z0 quad
    const int cb0 = z0 * 40 + qx;                  // coefficient quad index
    const int p0g0 = (g * 2) * SROW + 4 * qx;      // P0g index of row 0 quad
    const int zlim = min(130 - z0, RH);            // g<11: 11, g==11: 9
    const bool grec = act && (g == 2);             // this thread's r==9 is z=31
    const int xr0 = 4 * qx - 30;                   // receiver index of lane j=0

    const f2 c2v = { C2f, C2f };
    const f2 c3v = { C3f, C3f };

    float4 pA[RH];                      // p1, morphs into p_new via q-lag
    float4 p0r[9];                      // p0 rows 2..10
    #pragma unroll
    for (int r = 0; r < RH; ++r) pA[r] = make_float4(0.f, 0.f, 0.f, 0.f);
    #pragma unroll
    for (int r = 0; r < 9; ++r) p0r[r] = make_float4(0.f, 0.f, 0.f, 0.f);
    __syncthreads();

    for (int t = 0; t < 1000; ++t) {
        const float as = (t < 111) ? amp * Wv[t] : 0.0f;

        // ---- phase A: in-place stencil with 2-row q-lag ----
        if (act) {
            float4 hu2 = LD4(Ps, pc0 - 2 * SROW);
            float4 hu1 = LD4(Ps, pc0 - 1 * SROW);
            float4 hd1 = make_float4(0.f, 0.f, 0.f, 0.f);
            float4 hd2 = make_float4(0.f, 0.f, 0.f, 0.f);
            float4 qm2 = make_float4(0.f, 0.f, 0.f, 0.f);
            float4 qm1 = make_float4(0.f, 0.f, 0.f, 0.f);
            #pragma unroll
            for (int r = 0; r < RH; ++r) {
                if (r < zlim) {
                    if (r == 8) {                       // z-halo below, 1-row lead
                        hd1 = LD4(Ps, pc0 + RH * SROW);
                        hd2 = LD4(Ps, pc0 + (RH + 1) * SROW);
                    }
                    const int pc = pc0 + r * SROW;
                    f2 hl = LDF2(Ps, pc - 2);           // (c[-2], c[-1])
                    f2 hr = LDF2(Ps, pc + 4);           // (c[4],  c[5])
                    float4 al4 = AL4[cb0 + r * 40];
                    float4 t14 = T14[cb0 + r * 40];
                    float4 t24 = T24[cb0 + r * 40];     // negated temp2
                    float4 c  = pA[r];
                    float4 u1 = (r == 0) ? hu1 : pA[(r >= 1) ? r - 1 : 0];
                    float4 u2 = (r == 0) ? hu2 :
                                ((r == 1) ? hu1 : pA[(r >= 2) ? r - 2 : 0]);
                    float4 d1 = (r == RH - 1) ? hd1 : pA[(r + 1 < RH) ? r + 1 : 0];
                    float4 d2 = (r == RH - 1) ? hd2 :
                                ((r == RH - 2) ? hd1 : pA[(r + 2 < RH) ? r + 2 : 0]);
                    float4 p0 = (r < 2) ? LD4(P0g, p0g0 + r * SROW)
                                        : p0r[(r >= 2) ? r - 2 : 0];
                    // pair operands (cross-register shuffles left to compiler)
                    f2 cL = lo4(c), cH = hi4(c);
                    f2 l1L; l1L.x = hl.y; l1L.y = c.x;  // (c[-1], c0)
                    f2 r1L; r1L.x = c.y;  r1L.y = c.z;  // (c1, c2) == l1H
                    f2 r1H; r1H.x = c.w;  r1H.y = hr.x; // (c3, c4)
                    f2 qL = cellq_pk(hl,  l1L, cL, r1L, cH,
                                     lo4(u1), lo4(u2), lo4(d1), lo4(d2),
                                     lo4(al4), lo4(t14), lo4(t24), lo4(p0),
                                     c2v, c3v);
                    f2 qH = cellq_pk(cL,  r1L, cH, r1H, hr,
                                     hi4(u1), hi4(u2), hi4(d1), hi4(d2),
                                     hi4(al4), hi4(t14), hi4(t24), hi4(p0),
                                     c2v, c3v);
                    float4 q = make_float4(qL.x, qL.y, qH.x, qH.y);
                    if (r == 9 && isrc) {               // source injection (z=31)
                        q.x += (ls == 0) ? as : 0.0f;
                        q.y += (ls == 1) ? as : 0.0f;
                        q.z += (ls == 2) ? as : 0.0f;
                        q.w += (ls == 3) ? as : 0.0f;
                    }
                    if (r == 9 && grec) {               // receivers z=31, x=30..129
                        const int ob = shot * 100000 + t * 100 + xr0;
                        if (xr0 >= 0   && xr0 <= 99)  out[ob]     = q.x;
                        if (xr0 >= -1  && xr0 <= 98)  out[ob + 1] = q.y;
                        if (xr0 >= -2  && xr0 <= 97)  out[ob + 2] = q.z;
                        if (xr0 >= -3  && xr0 <= 96)  out[ob + 3] = q.w;
                    }
                    // p0 <- old p1 center (owner-private)
                    if (r < 2) ST4(P0g, p0g0 + r * SROW, c);
                    else       p0r[(r >= 2) ? r - 2 : 0] = c;
                    // q-lag commit: rows r-1, r have consumed old pA[r-2]
                    if (r >= 2) pA[(r >= 2) ? r - 2 : 0] = qm2;
                    qm2 = qm1;
                    qm1 = q;
                }
            }
            // tail: commit the last two rows
            if (zlim == 11) { pA[9] = qm2; pA[10] = qm1; }
            else            { pA[7] = qm2; pA[8] = qm1; }   // g == 11 (zlim 9)
        }
        __syncthreads();               // all Ps reads complete

        // ---- phase B: commit p_new (now in pA) to Ps ----
        if (act) {
            #pragma unroll
            for (int r = 0; r < RH; ++r)
                if (r < zlim) ST4(Ps, pc0 + r * SROW, pA[r]);
        }
        __syncthreads();               // new p1 visible for next step
    }
}

extern "C" void kernel_launch(void* const* d_in, const int* in_sizes, int n_in,
                              void* d_out, int out_size, void* d_ws, size_t ws_size,
                              hipStream_t stream) {
    const float* v = (const float*)d_in[0];
    float* ws = (float*)d_ws;                           // [0..999] wavelet, [1000..1009] amps, [1010] velmin
    float* AL = (float*)((char*)d_ws + 4096);           // 21120 floats (132 rows)
    float* T1 = (float*)((char*)d_ws + 4096 + 84480);   // 21120 floats
    float* T2 = (float*)((char*)d_ws + 4096 + 168960);  // 21120 floats (negated)
    float* out = (float*)d_out;

    fwi_setup1<<<1, 1024, 0, stream>>>(v, ws);
    fwi_setup2<<<83, 256, 0, stream>>>(v, ws, AL, T1, T2);
    fwi_main<<<10, 512, 0, stream>>>((const float4*)AL, (const float4*)T1,
                                     (const float4*)T2, ws, out);
}